// Round 6
// baseline (507.849 us; speedup 1.0000x reference)
//
#include <hip/hip_runtime.h>

#define DM    1024
#define NTOK  32768   // B*S
#define NRED  16384
#define NSAVE 16384
#define MMAX  16384   // max compacted rows
#define REPS  8       // measurement: gemm K-pass repeated 8x, exact (sum/8)

typedef __attribute__((ext_vector_type(8))) short bf16x8;
typedef __attribute__((ext_vector_type(4))) float f32x4;

__device__ __forceinline__ ushort f2bf(float f) {
    union { float f; unsigned u; } v; v.f = f;
    unsigned r = (v.u + 0x7FFF + ((v.u >> 16) & 1)) >> 16;   // RNE
    return (ushort)r;
}
__device__ __forceinline__ float bf2f(ushort u) {
    union { unsigned u; float f; } v; v.u = ((unsigned)u) << 16;
    return v.f;
}

// ---------------------------------------------------------------------------
__global__ __launch_bounds__(256) void setup_kernel(const float* __restrict__ W,
                                                    ushort* __restrict__ Wb,
                                                    int* __restrict__ cnt,
                                                    int* __restrict__ need,
                                                    int* __restrict__ counter) {
    int t = blockIdx.x * 256 + threadIdx.x;
    float4 v = ((const float4*)W)[t];
    ushort4 o;
    o.x = f2bf(v.x); o.y = f2bf(v.y); o.z = f2bf(v.z); o.w = f2bf(v.w);
    ((ushort4*)Wb)[t] = o;
    if (t < NTOK) { cnt[t] = 0; need[t] = 0; }
    if (t == 0) *counter = 0;
}

// ---------------------------------------------------------------------------
__global__ __launch_bounds__(256) void prep_kernel(const int* __restrict__ red,
                                                   const int* __restrict__ sav,
                                                   int* __restrict__ cnt,
                                                   int* __restrict__ need) {
    int j = blockIdx.x * 256 + threadIdx.x;
    if (j >= NRED) return;
    atomicAdd(&cnt[red[j]], 1);
    int s = sav[j];
    if (s > 0) need[s - 1] = 1;
}

// ---------------------------------------------------------------------------
__global__ __launch_bounds__(256) void compact_kernel(const int* __restrict__ cnt,
                                                      const int* __restrict__ need,
                                                      int* __restrict__ inv,
                                                      int* __restrict__ list,
                                                      int* __restrict__ counter) {
    int t = blockIdx.x * 256 + threadIdx.x;
    if (t >= NTOK) return;
    if (need[t] && cnt[t] > 0) {
        int pos = atomicAdd(counter, 1);
        inv[t] = pos;
        list[pos] = t;
    }
}

// ---------------------------------------------------------------------------
__global__ __launch_bounds__(256) void convx_kernel(const float* __restrict__ X,
                                                    const int* __restrict__ list,
                                                    const int* __restrict__ counter,
                                                    ushort* __restrict__ Xb) {
    const int M = *counter;
    const int Mpad = (M + 63) & ~63;
    for (int r = blockIdx.x; r < Mpad; r += gridDim.x) {
        ushort4 o;
        if (r < M) {
            int src = list[r];
            float4 v = ((const float4*)(X + (size_t)src * DM))[threadIdx.x];
            o.x = f2bf(v.x); o.y = f2bf(v.y); o.z = f2bf(v.z); o.w = f2bf(v.w);
        } else {
            o.x = 0; o.y = 0; o.z = 0; o.w = 0;
        }
        ((ushort4*)(Xb + (size_t)r * DM))[threadIdx.x] = o;
    }
}

// ---------------------------------------------------------------------------
// Single-wave bf16 MFMA GEMM, MEASUREMENT BUILD: the whole K-pass runs REPS=8
// times accumulating into the same fp32 acc (each rep adds an identical
// value; final scale by 1/8 is exact power-of-2), so this dispatch's duration
// = 8x the true GEMM cost and surfaces in rocprof's top-5 WITH counters.
// No DCE risk: every rep's MFMAs feed the stored output.
// ---------------------------------------------------------------------------
__global__ __launch_bounds__(64) void gemm_kernel(const ushort* __restrict__ Xb,
                                                  const ushort* __restrict__ Wb,
                                                  const int* __restrict__ counter,
                                                  ushort* __restrict__ Tb) {
    const int M = *counter;
    const int m0 = blockIdx.x * 64;
    if (m0 >= M) return;
    const int n0 = blockIdx.y * 64;

    __shared__ char lds[32768];      // 2 x (A 8KB + B 8KB)

    const int l = threadIdx.x;       // lane 0..63
    const int srow   = l >> 3;
    const int schunk = (l & 7) ^ (srow & 7);
    const ushort* aS = Xb + (size_t)(m0 + srow) * DM + schunk * 8;
    const ushort* bS = Wb + (size_t)(n0 + srow) * DM + schunk * 8;

#define STAGE(buf, k0) do {                                                         \
    char* _d = lds + (buf) * 16384;                                                 \
    _Pragma("unroll")                                                               \
    for (int _i = 0; _i < 8; ++_i) {                                                \
        __builtin_amdgcn_global_load_lds(                                           \
            (const __attribute__((address_space(1))) unsigned*)(aS + (k0) + _i * 8 * DM), \
            (__attribute__((address_space(3))) unsigned*)(_d + _i * 1024), 16, 0, 0);     \
        __builtin_amdgcn_global_load_lds(                                           \
            (const __attribute__((address_space(1))) unsigned*)(bS + (k0) + _i * 8 * DM), \
            (__attribute__((address_space(3))) unsigned*)(_d + 8192 + _i * 1024), 16, 0, 0); \
    }                                                                               \
} while (0)

    const int kgrp = l >> 4;
    const int r16  = l & 15;
    int off[4][2];
#pragma unroll
    for (int f = 0; f < 4; ++f) {
        int row = f * 16 + r16;
#pragma unroll
        for (int kk = 0; kk < 2; ++kk)
            off[f][kk] = row * 128 + (((kk * 4 + kgrp) ^ (row & 7)) * 16);
    }

    f32x4 acc[4][4] = {};

#pragma unroll 1
    for (int rep = 0; rep < REPS; ++rep) {
        asm volatile("s_waitcnt lgkmcnt(0)" ::: "memory");       // prev rep reads done
        STAGE(0, 0);
#pragma unroll
        for (int t = 0; t < 16; ++t) {
            const char* base = lds + (t & 1) * 16384;
            if (t < 15) {
                asm volatile("s_waitcnt lgkmcnt(0)" ::: "memory");
                __builtin_amdgcn_sched_barrier(0);
                STAGE((t & 1) ^ 1, (t + 1) * 64);
                asm volatile("s_waitcnt vmcnt(16)" ::: "memory");
                __builtin_amdgcn_sched_barrier(0);
            } else {
                asm volatile("s_waitcnt vmcnt(0)" ::: "memory");
                __builtin_amdgcn_sched_barrier(0);
            }
#pragma unroll
            for (int kk = 0; kk < 2; ++kk) {
                bf16x8 af[4], bfr[4];
#pragma unroll
                for (int f = 0; f < 4; ++f) af[f]  = *(const bf16x8*)(base + off[f][kk]);
#pragma unroll
                for (int f = 0; f < 4; ++f) bfr[f] = *(const bf16x8*)(base + 8192 + off[f][kk]);
#pragma unroll
                for (int i = 0; i < 4; ++i)
#pragma unroll
                    for (int j = 0; j < 4; ++j)
                        acc[i][j] = __builtin_amdgcn_mfma_f32_16x16x32_bf16(af[i], bfr[j], acc[i][j], 0, 0, 0);
            }
        }
    }
#undef STAGE

    // C/D layout: col = lane&15, row = (lane>>4)*4 + reg  [m89]; scale = 1/REPS
#pragma unroll
    for (int fm = 0; fm < 4; ++fm) {
        int mbase = m0 + fm * 16 + kgrp * 4;
#pragma unroll
        for (int fn = 0; fn < 4; ++fn) {
            int n = n0 + fn * 16 + r16;
#pragma unroll
            for (int r = 0; r < 4; ++r) {
                int m = mbase + r;
                if (m < M) Tb[(size_t)m * DM + n] = f2bf(acc[fm][fn][r] * 0.125f);
            }
        }
    }
}

// ---------------------------------------------------------------------------
__global__ __launch_bounds__(256) void out_kernel(const float* __restrict__ X,
                                                  const ushort* __restrict__ Tb,
                                                  const int* __restrict__ sav,
                                                  const int* __restrict__ cnt,
                                                  const int* __restrict__ inv,
                                                  float* __restrict__ out) {
    int r = blockIdx.x;
    int d = threadIdx.x;                 // float4 lane, 0..255
    int s = sav[r];
    const float4* xr = (const float4*)(X + (size_t)s * DM);
    float4 v = xr[d];
    if (s > 0) {
        int t = s - 1;
        int c = cnt[t];
        if (c > 0) {
            float fc = (float)c;
            const ushort4* tr = (const ushort4*)(Tb + (size_t)inv[t] * DM);
            ushort4 wv = tr[d];
            v.x += fc * bf2f(wv.x); v.y += fc * bf2f(wv.y);
            v.z += fc * bf2f(wv.z); v.w += fc * bf2f(wv.w);
        }
    }
    ((float4*)out)[(size_t)r * (DM / 4) + d] = v;
}

// ---------------------------------------------------------------------------
extern "C" void kernel_launch(void* const* d_in, const int* in_sizes, int n_in,
                              void* d_out, int out_size, void* d_ws, size_t ws_size,
                              hipStream_t stream) {
    const float* X   = (const float*)d_in[0];
    const float* W   = (const float*)d_in[1];
    const int*   sav = (const int*)d_in[2];   // ids_to_save
    const int*   red = (const int*)d_in[3];   // ids_to_reduce
    float* out = (float*)d_out;

    char* ws = (char*)d_ws;
    int* counter = (int*)ws;                  // 64 ints
    int* cnt  = counter + 64;                 // 32768
    int* need = cnt + NTOK;                   // 32768
    int* inv  = need + NTOK;                  // 32768
    int* list = inv + NTOK;                   // 16384  (ends < 512 KB)
    ushort* Wb = (ushort*)(ws + (1 << 19));   // 2 MB bf16 W
    ushort* Xb = (ushort*)(ws + (4 << 20));   // 32 MB bf16 compacted X rows (padded)
    ushort* Tb = (ushort*)(ws + (36u << 20)); // 32 MB bf16 T

    setup_kernel<<<DM * DM / 4 / 256, 256, 0, stream>>>(W, Wb, cnt, need, counter);
    prep_kernel<<<NRED / 256, 256, 0, stream>>>(red, sav, cnt, need);
    compact_kernel<<<NTOK / 256, 256, 0, stream>>>(cnt, need, inv, list, counter);
    convx_kernel<<<2048, 256, 0, stream>>>(X, list, counter, Xb);

    dim3 ggrid(MMAX / 64, DM / 64);           // x = m-blocks (256, early-exit), y = n (16)
    gemm_kernel<<<ggrid, 64, 0, stream>>>(Xb, Wb, counter, Tb);   // 8x amplified

    out_kernel<<<NSAVE, 256, 0, stream>>>(X, Tb, sav, cnt, inv, out);   // O, launch 1
    out_kernel<<<NSAVE, 256, 0, stream>>>(X, Tb, sav, cnt, inv, out);   // O, launch 2 (idempotent)
}

// Round 7
// 67.338 us; speedup vs baseline: 7.5418x; 7.5418x over previous
//
#include <hip/hip_runtime.h>

#define DM    1024
#define NTOK  32768   // B*S
#define NRED  16384
#define NSAVE 16384
#define MMAX  16384   // max compacted rows

typedef __attribute__((ext_vector_type(8))) short bf16x8;
typedef __attribute__((ext_vector_type(4))) float f32x4;

__device__ __forceinline__ ushort f2bf(float f) {
    union { float f; unsigned u; } v; v.f = f;
    unsigned r = (v.u + 0x7FFF + ((v.u >> 16) & 1)) >> 16;   // RNE
    return (ushort)r;
}
__device__ __forceinline__ float bf2f(ushort u) {
    union { unsigned u; float f; } v; v.u = ((unsigned)u) << 16;
    return v.f;
}

// ---------------------------------------------------------------------------
__global__ __launch_bounds__(256) void setup_kernel(const float* __restrict__ W,
                                                    ushort* __restrict__ Wb,
                                                    int* __restrict__ cnt,
                                                    int* __restrict__ need,
                                                    int* __restrict__ counter) {
    int t = blockIdx.x * 256 + threadIdx.x;
    float4 v = ((const float4*)W)[t];
    ushort4 o;
    o.x = f2bf(v.x); o.y = f2bf(v.y); o.z = f2bf(v.z); o.w = f2bf(v.w);
    ((ushort4*)Wb)[t] = o;
    if (t < NTOK) { cnt[t] = 0; need[t] = 0; }
    if (t == 0) *counter = 0;
}

// ---------------------------------------------------------------------------
__global__ __launch_bounds__(256) void prep_kernel(const int* __restrict__ red,
                                                   const int* __restrict__ sav,
                                                   int* __restrict__ cnt,
                                                   int* __restrict__ need) {
    int j = blockIdx.x * 256 + threadIdx.x;
    if (j >= NRED) return;
    atomicAdd(&cnt[red[j]], 1);
    int s = sav[j];
    if (s > 0) need[s - 1] = 1;
}

// ---------------------------------------------------------------------------
__global__ __launch_bounds__(256) void compact_kernel(const int* __restrict__ cnt,
                                                      const int* __restrict__ need,
                                                      int* __restrict__ inv,
                                                      int* __restrict__ list,
                                                      int* __restrict__ counter) {
    int t = blockIdx.x * 256 + threadIdx.x;
    if (t >= NTOK) return;
    if (need[t] && cnt[t] > 0) {
        int pos = atomicAdd(counter, 1);
        inv[t] = pos;
        list[pos] = t;
    }
}

// ---------------------------------------------------------------------------
// convx: gather + fp32->bf16 convert compacted rows; zero-pad to 128 multiple
// ---------------------------------------------------------------------------
__global__ __launch_bounds__(256) void convx_kernel(const float* __restrict__ X,
                                                    const int* __restrict__ list,
                                                    const int* __restrict__ counter,
                                                    ushort* __restrict__ Xb) {
    const int M = *counter;
    const int Mpad = (M + 127) & ~127;
    for (int r = blockIdx.x; r < Mpad; r += gridDim.x) {
        ushort4 o;
        if (r < M) {
            int src = list[r];
            float4 v = ((const float4*)(X + (size_t)src * DM))[threadIdx.x];
            o.x = f2bf(v.x); o.y = f2bf(v.y); o.z = f2bf(v.z); o.w = f2bf(v.w);
        } else {
            o.x = 0; o.y = 0; o.z = 0; o.w = 0;
        }
        ((ushort4*)(Xb + (size_t)r * DM))[threadIdx.x] = o;
    }
}

// ---------------------------------------------------------------------------
// bf16 MFMA GEMM: Tb[m,n] = bf16( sum_k Xb[m,k] * Wb[n,k] )
// BM=BN=128, BK=64, 4 waves (256 thr); wave w owns m-rows [w*32, w*32+32)
// x all 128 n (2 m-frags x 8 n-frags x 2 k-slices = 32 MFMA/step, acc 2x8).
// Staging: per step 32 KB via 32 x global_load_lds(16) (8 per wave, zero
// duplication), source pre-swizzled chunk^=(row&7) (rule #21) -> swizzled
// ds_read_b128 2-way = free (m136). Double-buffered with counted vmcnt(8)
// + raw s_barrier: next-buf loads stay in flight across the barrier (T4,
// never vmcnt(0) mid-loop). LDS 64 KB -> 2 wg/CU = 8 waves/CU.
// Grid x=mblk: consecutive x round-robin XCDs; per XCD A-band 1.25MB + whole
// Wb 2MB stay L2-resident.
// ---------------------------------------------------------------------------
__global__ __launch_bounds__(256) void gemm_kernel(const ushort* __restrict__ Xb,
                                                   const ushort* __restrict__ Wb,
                                                   const int* __restrict__ counter,
                                                   ushort* __restrict__ Tb) {
    const int M = *counter;
    const int m0 = blockIdx.x * 128;
    if (m0 >= M) return;                 // uniform exit before any barrier
    const int n0 = blockIdx.y * 128;

    __shared__ char lds[65536];          // 2 bufs x (A 16KB + B 16KB)

    const int tid  = threadIdx.x;
    const int l    = tid & 63;
    const int w    = tid >> 6;

    // staging: instr i covers rows w*32+i*8 .. +8; lane: row+=(l>>3), chunk l&7
    const int srow   = l >> 3;
    const int schunk = (l & 7) ^ (srow & 7);     // logical chunk for stored slot l&7
    const ushort* aS = Xb + (size_t)(m0 + w * 32 + srow) * DM + schunk * 8;
    const ushort* bS = Wb + (size_t)(n0 + w * 32 + srow) * DM + schunk * 8;
    const int dOff   = (w * 32) * 128;           // byte offset of wave's row band

#define STAGE(buf, k0) do {                                                          \
    char* _a = lds + (buf) * 32768 + dOff;                                           \
    _Pragma("unroll")                                                                \
    for (int _i = 0; _i < 4; ++_i) {                                                 \
        __builtin_amdgcn_global_load_lds(                                            \
            (const __attribute__((address_space(1))) unsigned*)(aS + (k0) + _i * 8 * DM), \
            (__attribute__((address_space(3))) unsigned*)(_a + _i * 1024), 16, 0, 0);      \
        __builtin_amdgcn_global_load_lds(                                            \
            (const __attribute__((address_space(1))) unsigned*)(bS + (k0) + _i * 8 * DM), \
            (__attribute__((address_space(3))) unsigned*)(_a + 16384 + _i * 1024), 16, 0, 0); \
    }                                                                                \
} while (0)

    // fragment read byte-offsets (within buf): row-major [row][chunk^(row&7)]
    const int kgrp = l >> 4;
    const int r16  = l & 15;
    int aoff[2][2], boff[8][2];
#pragma unroll
    for (int fm = 0; fm < 2; ++fm) {
        int row = w * 32 + fm * 16 + r16;
#pragma unroll
        for (int kk = 0; kk < 2; ++kk)
            aoff[fm][kk] = row * 128 + (((kk * 4 + kgrp) ^ (row & 7)) * 16);
    }
#pragma unroll
    for (int fn = 0; fn < 8; ++fn) {
        int row = fn * 16 + r16;
#pragma unroll
        for (int kk = 0; kk < 2; ++kk)
            boff[fn][kk] = 16384 + row * 128 + (((kk * 4 + kgrp) ^ (row & 7)) * 16);
    }

    f32x4 acc[2][8] = {};

    STAGE(0, 0);
#pragma unroll
    for (int t = 0; t < 16; ++t) {
        const char* base = lds + (t & 1) * 32768;
        if (t < 15) {
            STAGE((t & 1) ^ 1, (t + 1) * 64);
            asm volatile("s_waitcnt vmcnt(8)" ::: "memory");   // my cur-buf loads landed
        } else {
            asm volatile("s_waitcnt vmcnt(0)" ::: "memory");
        }
        __builtin_amdgcn_sched_barrier(0);
        __builtin_amdgcn_s_barrier();                          // everyone's cur loads landed

#pragma unroll
        for (int kk = 0; kk < 2; ++kk) {
            bf16x8 af[2], bfr[8];
#pragma unroll
            for (int fm = 0; fm < 2; ++fm) af[fm]  = *(const bf16x8*)(base + aoff[fm][kk]);
#pragma unroll
            for (int fn = 0; fn < 8; ++fn) bfr[fn] = *(const bf16x8*)(base + boff[fn][kk]);
#pragma unroll
            for (int fm = 0; fm < 2; ++fm)
#pragma unroll
                for (int fn = 0; fn < 8; ++fn)
                    acc[fm][fn] = __builtin_amdgcn_mfma_f32_16x16x32_bf16(af[fm], bfr[fn], acc[fm][fn], 0, 0, 0);
        }

        if (t < 15)
            __builtin_amdgcn_s_barrier();   // all reads of cur done -> next STAGE may overwrite
    }
#undef STAGE

    // C/D layout: col = lane&15, row = (lane>>4)*4 + reg  [m89]
#pragma unroll
    for (int fm = 0; fm < 2; ++fm) {
        int mbase = m0 + w * 32 + fm * 16 + kgrp * 4;
#pragma unroll
        for (int fn = 0; fn < 8; ++fn) {
            int n = n0 + fn * 16 + r16;
#pragma unroll
            for (int r = 0; r < 4; ++r) {
                int m = mbase + r;
                if (m < M) Tb[(size_t)m * DM + n] = f2bf(acc[fm][fn][r]);
            }
        }
    }
}

// ---------------------------------------------------------------------------
// epilogue: out[r] = x[s] + cnt[s-1] * Tb[inv[s-1]]
// ---------------------------------------------------------------------------
__global__ __launch_bounds__(256) void out_kernel(const float* __restrict__ X,
                                                  const ushort* __restrict__ Tb,
                                                  const int* __restrict__ sav,
                                                  const int* __restrict__ cnt,
                                                  const int* __restrict__ inv,
                                                  float* __restrict__ out) {
    int r = blockIdx.x;
    int d = threadIdx.x;                 // float4 lane, 0..255
    int s = sav[r];
    const float4* xr = (const float4*)(X + (size_t)s * DM);
    float4 v = xr[d];
    if (s > 0) {
        int t = s - 1;
        int c = cnt[t];
        if (c > 0) {
            float fc = (float)c;
            const ushort4* tr = (const ushort4*)(Tb + (size_t)inv[t] * DM);
            ushort4 wv = tr[d];
            v.x += fc * bf2f(wv.x); v.y += fc * bf2f(wv.y);
            v.z += fc * bf2f(wv.z); v.w += fc * bf2f(wv.w);
        }
    }
    ((float4*)out)[(size_t)r * (DM / 4) + d] = v;
}

// ---------------------------------------------------------------------------
extern "C" void kernel_launch(void* const* d_in, const int* in_sizes, int n_in,
                              void* d_out, int out_size, void* d_ws, size_t ws_size,
                              hipStream_t stream) {
    const float* X   = (const float*)d_in[0];
    const float* W   = (const float*)d_in[1];
    const int*   sav = (const int*)d_in[2];   // ids_to_save
    const int*   red = (const int*)d_in[3];   // ids_to_reduce
    float* out = (float*)d_out;

    char* ws = (char*)d_ws;
    int* counter = (int*)ws;                  // 64 ints
    int* cnt  = counter + 64;                 // 32768
    int* need = cnt + NTOK;                   // 32768
    int* inv  = need + NTOK;                  // 32768
    int* list = inv + NTOK;                   // 16384  (ends < 512 KB)
    ushort* Wb = (ushort*)(ws + (1 << 19));   // 2 MB bf16 W
    ushort* Xb = (ushort*)(ws + (4 << 20));   // 32 MB bf16 compacted X rows (padded)
    ushort* Tb = (ushort*)(ws + (36u << 20)); // 32 MB bf16 T

    setup_kernel<<<DM * DM / 4 / 256, 256, 0, stream>>>(W, Wb, cnt, need, counter);
    prep_kernel<<<NRED / 256, 256, 0, stream>>>(red, sav, cnt, need);
    compact_kernel<<<NTOK / 256, 256, 0, stream>>>(cnt, need, inv, list, counter);
    convx_kernel<<<2048, 256, 0, stream>>>(X, list, counter, Xb);

    dim3 ggrid(MMAX / 128, DM / 128);         // x = m-blocks (128, early-exit), y = n (8)
    gemm_kernel<<<ggrid, 256, 0, stream>>>(Xb, Wb, counter, Tb);

    out_kernel<<<NSAVE, 256, 0, stream>>>(X, Tb, sav, cnt, inv, out);
}